// Round 4
// baseline (613.518 us; speedup 1.0000x reference)
//
#include <hip/hip_runtime.h>

#define BATCH 4
#define T 8192
#define RES 256
#define SKIPC 512
#define NCLSC 256
#define NLAYERS 30
#define T0 5120
#define TBUF 3072
#define NT 32
#define STR 264               // LDS row stride in shorts (528 B): 2-way banks, 16B-aligned
#define TAPSZ (NT * STR)      // 8448 shorts per tap buffer
#define GRIDP 384             // tiles(96) x batch(4); 2 blocks/CU -> all co-resident
#define MAXTILES 96

typedef __attribute__((ext_vector_type(8))) short short8x;   // 8 bf16
typedef __attribute__((ext_vector_type(4))) float floatx4;   // MFMA C/D
typedef unsigned short ushort_t;
typedef unsigned long long ull;

__device__ __forceinline__ ushort_t f2bf(float f) {
    unsigned u = __float_as_uint(f);
    u += 0x7fffu + ((u >> 16) & 1u);
    return (ushort_t)(u >> 16);
}
__device__ __forceinline__ float bf2f(ushort_t h) {
    return __uint_as_float(((unsigned)h) << 16);
}

// Coherent (cross-XCD) 8B access: relaxed agent-scope atomics -> sc1 ops, no
// cache-maintenance. Used ONLY for the tap0 halo (hbC) and flags; everything
// else is plain-cached (same-block producer/consumer -> own L1/L2).
__device__ __forceinline__ ull cload(const ull* p) {
    return __hip_atomic_load(p, __ATOMIC_RELAXED, __HIP_MEMORY_SCOPE_AGENT);
}
__device__ __forceinline__ void cstore(ull* p, ull v) {
    __hip_atomic_store(p, v, __ATOMIC_RELAXED, __HIP_MEMORY_SCOPE_AGENT);
}

#define WAITF(P) while (__hip_atomic_load((P), __ATOMIC_RELAXED, __HIP_MEMORY_SCOPE_AGENT) == 0) \
                     __builtin_amdgcn_s_sleep(1)

// Weight prep: Aswz/Rswz in exact MFMA A-fragment load order (coalesced loads).
__global__ __launch_bounds__(256) void prep_kernel(
    const float* __restrict__ Wd, const float* __restrict__ Wr,
    const float* __restrict__ Ws,
    ushort_t* __restrict__ Aswz, ushort_t* __restrict__ Rswz,
    ushort_t* __restrict__ WsT)
{
    long id = (long)blockIdx.x * 256 + threadIdx.x;
    const long R0 = 30L * 131072, R1 = 30L * 65536, R2 = 30L * 131072;
    if (id < R0) {
        long l = id >> 17; int r = (int)(id & 131071);
        int j = r & 7, lane = (r >> 3) & 63, f = (r >> 9) & 1, s = (r >> 10) & 15, wv = r >> 14;
        int row = wv * 32 + f * 16 + (lane & 15);
        int k = s * 32 + (lane >> 4) * 8 + j;
        int cin = k & 255, kk = k >> 8;
        Aswz[id] = f2bf(Wd[((l * 256 + row) * 256 + cin) * 2 + kk]);
        return;
    }
    id -= R0;
    if (id < R1) {
        long l = id >> 16; int r = (int)(id & 65535);
        int j = r & 7, lane = (r >> 3) & 63, f = (r >> 9) & 1, s = (r >> 10) & 7, wv = r >> 13;
        int row = wv * 32 + f * 16 + (lane & 15);
        int k = s * 32 + (lane >> 4) * 8 + j;
        Rswz[id] = f2bf(Wr[(l * 256 + row) * 256 + k]);
        return;
    }
    id -= R1;
    if (id < R2) {
        int o = (int)(id & 511); long rest = id >> 9; int cin = (int)(rest & 255); long l = rest >> 8;
        WsT[id] = f2bf(Ws[(l * 512 + o) * 256 + cin]);
    }
}

// h0[b][t][c] for t in [5120, 8191], fp32 + bf16 copies.
__global__ __launch_bounds__(256) void start_kernel(
    const float* __restrict__ x, const float* __restrict__ Wst,
    const float* __restrict__ bst, float* __restrict__ hf, ushort_t* __restrict__ hb)
{
    int id = blockIdx.x * 256 + threadIdx.x;
    int c = id & 255;
    int ti = (id >> 8) % TBUF;
    int b  = (id >> 8) / TBUF;
    int t = T0 + ti;
    float v = Wst[2 * c] * x[b * T + t - 1] + Wst[2 * c + 1] * x[b * T + t] + bst[c];
    hf[id] = v;
    hb[id] = f2bf(v);
}

// All 30 layers dataflow-pipelined, layer-stable tile<->block mapping.
// v4: (a) conv/res A-fragments explicitly preloaded in 16-frag bursts so L2
// latency is paid once per GEMM half instead of per K-step (round-3 VGPR=48
// showed zero pipelining); (b) flag wait + remote halo staging moved BETWEEN
// the conv halves (tap1 half has no remote dependency) so the hop latency
// hides under MFMA work; (c) epilogue publishes the halo columns + flag
// BEFORE the remaining writes.
__global__ __launch_bounds__(512, 4) void fused_layers_kernel(
    float* __restrict__ hf,
    ushort_t* __restrict__ hb0, ushort_t* __restrict__ hb1,
    const ushort_t* __restrict__ Asw,
    const float* __restrict__ bd,
    const ushort_t* __restrict__ Rsw,
    const float* __restrict__ br,
    float* __restrict__ gstore,
    ushort_t* __restrict__ hbC,
    int* __restrict__ flg)
{
    __shared__ __align__(16) ushort_t st[2 * TAPSZ];   // 33.8 KB; gated overlays tap0

    const int tid = threadIdx.x;
    const int wv = tid >> 6, lane = tid & 63;
    const int quad = lane >> 4, l16 = lane & 15;
    const int mb = wv * 32;
    const int u0 = l16 * STR + quad * 8;
    const int u1 = u0 + 16 * STR;
    const int B = blockIdx.x;
    const int tile = B >> 2;          // stable across layers (ntiles shrinks)
    const int b = B & 3;
    const int tb = 8192 - NT * (tile + 1);

    float* __restrict__ hfb = hf + (size_t)b * TBUF * RES;

    int rem = 3069;
    int ntiles_prev = 0;
    size_t cur_off = 0, prev_off = 0;

    for (int i = 0; i < NLAYERS; ++i) {
        const int dil = 1 << (i % 10);
        rem -= dil;                                    // rem[i+1]
        const int s_out = 8191 - rem;
        const int ntiles = (8192 - s_out + NT - 1) >> 5;
        if (tile >= ntiles) break;                     // shrinking: done forever

        const ushort_t* __restrict__ hA = ((i & 1) ? hb1 : hb0) + (size_t)b * TBUF * RES;
        ushort_t* __restrict__ hB = ((i & 1) ? hb0 : hb1) + (size_t)b * TBUF * RES;
        const ushort_t* __restrict__ aw =
            Asw + (size_t)i * (RES * 512) + (size_t)wv * 16384 + lane * 8;
        const ushort_t* __restrict__ rw =
            Rsw + (size_t)i * (RES * RES) + (size_t)wv * 8192 + lane * 8;
        const float* __restrict__ bdL = bd + i * RES;
        const float* __restrict__ brL = br + i * RES;

        // ---- remote tap0 halo bookkeeping ----
        const int dil_eff = (i == 0) ? 0 : (dil < 32 ? dil : 32);   // remote rows [0, dil_eff)
        const int rdelta = (dil < 32) ? 1 : (dil >> 5);
        const int r = tile + rdelta;                   // single remote producer tile
        const bool remote_valid = (i > 0) && (r < ntiles_prev);
        const ushort_t* hbCp = nullptr;
        if (remote_valid)
            hbCp = hbC + prev_off + ((size_t)b * ntiles_prev + r) * (size_t)dil_eff * RES;

        __syncthreads();   // prev unit's res-GEMM LDS reads done before restaging

        // Stage tap1 (all rows, own data) + tap0 own rows (row >= dil_eff).
        // Remote rows of tap0 are staged later, after the flag, hidden under
        // conv-half-tap1. Rows < dil_eff with !remote_valid stay stale: they
        // only feed columns t < s_out which the epilogue discards.
        #pragma unroll
        for (int p = 0; p < 2; ++p) {
            int c = p * 512 + tid;
            int row = c >> 5, offs = (c & 31) * 8;
            const ull* src = (const ull*)(hA + (size_t)(tb + row - T0) * RES + offs);
            ull v0 = src[0], v1 = src[1];
            ull* dst = (ull*)&st[TAPSZ + row * STR + offs];
            dst[0] = v0; dst[1] = v1;
        }
        #pragma unroll
        for (int p = 0; p < 2; ++p) {
            int c = p * 512 + tid;
            int row = c >> 5, offs = (c & 31) * 8;
            if (row >= dil_eff) {
                int tt = tb + row - dil - T0;
                tt = tt < 0 ? 0 : tt;              // junk cols discarded in epilogue
                const ull* src = (const ull*)(hA + (size_t)tt * RES + offs);
                ull v0 = src[0], v1 = src[1];
                ull* dst = (ull*)&st[row * STR + offs];
                dst[0] = v0; dst[1] = v1;
            }
        }
        __syncthreads();

        floatx4 acc00, acc01, acc10, acc11;
        {
            float4 c0 = *(const float4*)(bdL + mb + quad * 4);
            float4 c1 = *(const float4*)(bdL + mb + 16 + quad * 4);
            acc00 = acc01 = (floatx4){c0.x, c0.y, c0.z, c0.w};
            acc10 = acc11 = (floatx4){c1.x, c1.y, c1.z, c1.w};
        }

        // Preload conv-half-tap1 A-fragments (16 frags = 64 VGPR), then MFMA.
        short8x A[16];
        #pragma unroll
        for (int s = 0; s < 8; ++s) {
            A[2 * s]     = *(const short8x*)(aw + (s + 8) * 1024);
            A[2 * s + 1] = *(const short8x*)(aw + (s + 8) * 1024 + 512);
        }
        #pragma unroll
        for (int s = 0; s < 8; ++s) {
            const int tbs = TAPSZ + s * 32;
            short8x g0 = *(const short8x*)&st[tbs + u0];
            short8x g1 = *(const short8x*)&st[tbs + u1];
            acc00 = __builtin_amdgcn_mfma_f32_16x16x32_bf16(A[2*s],   g0, acc00, 0, 0, 0);
            acc10 = __builtin_amdgcn_mfma_f32_16x16x32_bf16(A[2*s+1], g0, acc10, 0, 0, 0);
            acc01 = __builtin_amdgcn_mfma_f32_16x16x32_bf16(A[2*s],   g1, acc01, 0, 0, 0);
            acc11 = __builtin_amdgcn_mfma_f32_16x16x32_bf16(A[2*s+1], g1, acc11, 0, 0, 0);
        }

        // Issue conv-half-tap0 A-loads now: they fly during the flag wait.
        #pragma unroll
        for (int s = 0; s < 8; ++s) {
            A[2 * s]     = *(const short8x*)(aw + s * 1024);
            A[2 * s + 1] = *(const short8x*)(aw + s * 1024 + 512);
        }

        // Flag wait + remote halo staging (<= 2 coherent 16B loads/thread).
        if (remote_valid) {
            if (tid == 0) WAITF(flg + ((i - 1) * BATCH + b) * MAXTILES + r);
            __syncthreads();
            #pragma unroll
            for (int p = 0; p < 2; ++p) {
                int c = p * 512 + tid;
                int row = c >> 5, offs = (c & 31) * 8;
                if (row < dil_eff) {
                    const ull* src = (const ull*)(hbCp + (size_t)row * RES + offs);
                    ull v0 = cload(src), v1 = cload(src + 1);
                    ull* dst = (ull*)&st[row * STR + offs];
                    dst[0] = v0; dst[1] = v1;
                }
            }
            __syncthreads();
        }

        // Conv-half-tap0
        #pragma unroll
        for (int s = 0; s < 8; ++s) {
            const int tbs = s * 32;
            short8x g0 = *(const short8x*)&st[tbs + u0];
            short8x g1 = *(const short8x*)&st[tbs + u1];
            acc00 = __builtin_amdgcn_mfma_f32_16x16x32_bf16(A[2*s],   g0, acc00, 0, 0, 0);
            acc10 = __builtin_amdgcn_mfma_f32_16x16x32_bf16(A[2*s+1], g0, acc10, 0, 0, 0);
            acc01 = __builtin_amdgcn_mfma_f32_16x16x32_bf16(A[2*s],   g1, acc01, 0, 0, 0);
            acc11 = __builtin_amdgcn_mfma_f32_16x16x32_bf16(A[2*s+1], g1, acc11, 0, 0, 0);
        }

        // Issue residual A-fragments now (fly under the gate VALU phase).
        short8x R[16];
        #pragma unroll
        for (int s = 0; s < 8; ++s) {
            R[2 * s]     = *(const short8x*)(rw + s * 1024);
            R[2 * s + 1] = *(const short8x*)(rw + s * 1024 + 512);
        }

        __syncthreads();   // conv LDS reads done before gate overlays tap0

        // gate -> LDS gl[n][cin] (overlay tap0); capture t=8191 col fp32
        #pragma unroll
        for (int mt = 0; mt < 2; ++mt) {
            #pragma unroll
            for (int nt = 0; nt < 2; ++nt) {
                floatx4 a = mt == 0 ? (nt == 0 ? acc00 : acc01) : (nt == 0 ? acc10 : acc11);
                float gf[4];
                ull pk = 0;
                #pragma unroll
                for (int rr = 0; rr < 4; ++rr) {
                    float d = a[rr];
                    float sig = 1.f / (1.f + __expf(-d));
                    float th = 1.f - 2.f / (__expf(2.f * d) + 1.f);
                    gf[rr] = th * sig;
                    pk |= ((ull)f2bf(gf[rr])) << (16 * rr);
                }
                const int n = nt * 16 + l16;
                const int m = mb + mt * 16 + quad * 4;
                *(ull*)&st[n * STR + m] = pk;
                if (tile == 0 && n == 31) {
                    float4 g4 = {gf[0], gf[1], gf[2], gf[3]};
                    *(float4*)&gstore[((size_t)i * BATCH + b) * RES + m] = g4;
                }
            }
        }
        __syncthreads();

        // Residual GEMM: h' = h + Wr @ gated, K=256
        floatx4 r00, r01, r10, r11;
        {
            float4 c0 = *(const float4*)(brL + mb + quad * 4);
            float4 c1 = *(const float4*)(brL + mb + 16 + quad * 4);
            r00 = r01 = (floatx4){c0.x, c0.y, c0.z, c0.w};
            r10 = r11 = (floatx4){c1.x, c1.y, c1.z, c1.w};
        }
        #pragma unroll
        for (int s = 0; s < 8; ++s) {
            short8x g0 = *(const short8x*)&st[s * 32 + u0];
            short8x g1 = *(const short8x*)&st[s * 32 + u1];
            r00 = __builtin_amdgcn_mfma_f32_16x16x32_bf16(R[2*s],   g0, r00, 0, 0, 0);
            r10 = __builtin_amdgcn_mfma_f32_16x16x32_bf16(R[2*s+1], g0, r10, 0, 0, 0);
            r01 = __builtin_amdgcn_mfma_f32_16x16x32_bf16(R[2*s],   g1, r01, 0, 0, 0);
            r11 = __builtin_amdgcn_mfma_f32_16x16x32_bf16(R[2*s+1], g1, r11, 0, 0, 0);
        }

        // ---- halo publish bookkeeping for THIS layer's output ----
        const int dnext = (i < NLAYERS - 1) ? (1 << ((i + 1) % 10)) : 0;
        const int Ci = (dnext < 32) ? dnext : 32;      // 0 when i==29
        const int dnx = (dnext >= 32) ? (dnext >> 5) : 1;
        const bool wrC = (Ci > 0) && (tile >= dnx);    // has a consumer
        ushort_t* hbCc = hbC + cur_off + ((size_t)b * ntiles + tile) * (size_t)Ci * RES;
        const int tminC = tb + 32 - Ci;

        // Epilogue, publish-first: halo cols live in nt=1 when Ci<=16.
        #define EPILOG(NTV, RA, RB, DOHALO) do {                                   \
            const int t = tb + (NTV) * 16 + l16;                                   \
            if (t >= s_out) {                                                      \
                const size_t base = (size_t)(t - T0) * RES;                        \
                _Pragma("unroll")                                                  \
                for (int mt = 0; mt < 2; ++mt) {                                   \
                    const int m = mb + mt * 16 + quad * 4;                         \
                    floatx4 ad = mt == 0 ? (RA) : (RB);                            \
                    float4 ho = *(const float4*)(hfb + base + m);                  \
                    float4 hn = {ho.x + ad[0], ho.y + ad[1],                       \
                                 ho.z + ad[2], ho.w + ad[3]};                      \
                    *(float4*)(hfb + base + m) = hn;                               \
                    ull pk = (ull)f2bf(hn.x) | ((ull)f2bf(hn.y) << 16)             \
                           | ((ull)f2bf(hn.z) << 32) | ((ull)f2bf(hn.w) << 48);    \
                    *(ull*)(hB + base + m) = pk;                                   \
                    if ((DOHALO) && wrC && t >= tminC)                             \
                        cstore((ull*)(hbCc + (size_t)(t - tminC) * RES + m), pk);  \
                }                                                                  \
            }                                                                      \
        } while (0)

        EPILOG(1, r01, r11, true);
        if (Ci == 32) EPILOG(0, r00, r10, true);
        asm volatile("s_waitcnt vmcnt(0)" ::: "memory");
        __syncthreads();
        if (tid == 0)
            __hip_atomic_store(flg + ((size_t)i * BATCH + b) * MAXTILES + tile, 1,
                               __ATOMIC_RELAXED, __HIP_MEMORY_SCOPE_AGENT);
        if (Ci != 32) EPILOG(0, r00, r10, false);
        #undef EPILOG

        ntiles_prev = ntiles;
        prev_off = cur_off;
        cur_off += (size_t)4 * ntiles * Ci * RES;
    }
}

// All 30 skip matvecs in parallel: block (l,b), thread o
__global__ __launch_bounds__(512) void skip_kernel(
    const ushort_t* __restrict__ WsT, const float* __restrict__ bs,
    const float* __restrict__ gstore, float* __restrict__ skip)
{
    const int l = blockIdx.x, b = blockIdx.y, o = threadIdx.x;
    const ushort_t* w = WsT + (size_t)l * 131072;
    const float* g = gstore + (size_t)(l * BATCH + b) * RES;
    float a = bs[l * SKIPC + o];
    #pragma unroll 4
    for (int cin = 0; cin < RES; ++cin)
        a = fmaf(bf2f(w[cin * SKIPC + o]), g[cin], a);
    atomicAdd(&skip[b * SKIPC + o], a);
}

// e1[b][o] = relu(W1 @ relu(skip[b]) + b1); grid (B, 16), block computes 32 outputs
__global__ __launch_bounds__(256) void end1_kernel(
    const float* __restrict__ skip, const float* __restrict__ W1,
    const float* __restrict__ b1, float* __restrict__ e1ws)
{
    __shared__ float s[SKIPC];
    __shared__ float part[256];
    const int b = blockIdx.x, og = blockIdx.y, tid = threadIdx.x;
    s[tid]       = fmaxf(skip[b * SKIPC + tid], 0.f);
    s[tid + 256] = fmaxf(skip[b * SKIPC + tid + 256], 0.f);
    __syncthreads();
    const int o_l = tid >> 3, kp = tid & 7;
    const int o = og * 32 + o_l;
    const float* w = W1 + (size_t)o * SKIPC + kp * 64;
    const float* sp = s + kp * 64;
    float a = 0.f;
    #pragma unroll 8
    for (int j = 0; j < 64; ++j) a = fmaf(w[j], sp[j], a);
    part[tid] = a;
    __syncthreads();
    if (tid < 32) {
        float r = b1[og * 32 + tid];
        #pragma unroll
        for (int k = 0; k < 8; ++k) r += part[tid * 8 + k];
        e1ws[b * SKIPC + og * 32 + tid] = fmaxf(r, 0.f);
    }
}

// out[b][cls] = W2 @ e1 + b2; grid (B, 8), block computes 32 outputs
__global__ __launch_bounds__(256) void end2_kernel(
    const float* __restrict__ e1ws, const float* __restrict__ W2,
    const float* __restrict__ b2, float* __restrict__ out)
{
    __shared__ float e[SKIPC];
    __shared__ float part[256];
    const int b = blockIdx.x, og = blockIdx.y, tid = threadIdx.x;
    e[tid]       = e1ws[b * SKIPC + tid];
    e[tid + 256] = e1ws[b * SKIPC + tid + 256];
    __syncthreads();
    const int o_l = tid >> 3, kp = tid & 7;
    const int cls = og * 32 + o_l;
    const float* w = W2 + (size_t)cls * SKIPC + kp * 64;
    const float* ep = e + kp * 64;
    float a = 0.f;
    #pragma unroll 8
    for (int j = 0; j < 64; ++j) a = fmaf(w[j], ep[j], a);
    part[tid] = a;
    __syncthreads();
    if (tid < 32) {
        float r = b2[og * 32 + tid];
        #pragma unroll
        for (int k = 0; k < 8; ++k) r += part[tid * 8 + k];
        out[b * NCLSC + og * 32 + tid] = r;
    }
}

extern "C" void kernel_launch(void* const* d_in, const int* in_sizes, int n_in,
                              void* d_out, int out_size, void* d_ws, size_t ws_size,
                              hipStream_t stream)
{
    const float* x   = (const float*)d_in[0];
    const float* Wst = (const float*)d_in[1];
    const float* bst = (const float*)d_in[2];
    const float* Wd  = (const float*)d_in[3];
    const float* bd  = (const float*)d_in[4];
    const float* Wr  = (const float*)d_in[5];
    const float* br  = (const float*)d_in[6];
    const float* Ws  = (const float*)d_in[7];
    const float* bs  = (const float*)d_in[8];
    const float* W1  = (const float*)d_in[9];
    const float* b1  = (const float*)d_in[10];
    const float* W2  = (const float*)d_in[11];
    const float* b2  = (const float*)d_in[12];
    float* out = (float*)d_out;

    // hbC size: per layer, 4 * ntiles * C cols of 256 bf16 (C = min(dil_next,32))
    size_t hbC_shorts = 0;
    {
        int rem = 3069;
        for (int i = 0; i < NLAYERS; ++i) {
            int d = 1 << (i % 10);
            rem -= d;
            int ntl = (1 + rem + 31) >> 5;
            int dn = (i < NLAYERS - 1) ? (1 << ((i + 1) % 10)) : 0;
            int Ci = (dn < 32) ? dn : 32;
            hbC_shorts += (size_t)4 * ntl * Ci * RES;
        }
    }

    char* w = (char*)d_ws;
    float* hf     = (float*)w;     w += (size_t)BATCH * TBUF * RES * 4;
    ushort_t* hb0 = (ushort_t*)w;  w += (size_t)BATCH * TBUF * RES * 2;
    ushort_t* hb1 = (ushort_t*)w;  w += (size_t)BATCH * TBUF * RES * 2;
    ushort_t* Asw = (ushort_t*)w;  w += (size_t)NLAYERS * RES * 512 * 2;
    ushort_t* Rsw = (ushort_t*)w;  w += (size_t)NLAYERS * RES * RES * 2;
    ushort_t* WsT = (ushort_t*)w;  w += (size_t)NLAYERS * RES * SKIPC * 2;
    float* gstore = (float*)w;     w += (size_t)NLAYERS * BATCH * RES * 4;
    float* skip   = (float*)w;     w += (size_t)BATCH * SKIPC * 4;
    float* e1ws   = (float*)w;     w += (size_t)BATCH * SKIPC * 4;
    ushort_t* hbC = (ushort_t*)w;  w += hbC_shorts * 2;
    int* flg      = (int*)w;       w += (size_t)NLAYERS * BATCH * MAXTILES * 4;

    prep_kernel<<<38400, 256, 0, stream>>>(Wd, Wr, Ws, Asw, Rsw, WsT);
    start_kernel<<<(BATCH * TBUF * RES) / 256, 256, 0, stream>>>(x, Wst, bst, hf, hb0);
    hipMemsetAsync(skip, 0, BATCH * SKIPC * 4, stream);
    hipMemsetAsync(flg, 0, (size_t)NLAYERS * BATCH * MAXTILES * 4, stream);

    fused_layers_kernel<<<GRIDP, 512, 0, stream>>>(
        hf, hb0, hb1, Asw, bd, Rsw, br, gstore, hbC, flg);

    skip_kernel<<<dim3(NLAYERS, BATCH), 512, 0, stream>>>(WsT, bs, gstore, skip);
    end1_kernel<<<dim3(BATCH, 16), 256, 0, stream>>>(skip, W1, b1, e1ws);
    end2_kernel<<<dim3(BATCH, 8), 256, 0, stream>>>(e1ws, W2, b2, out);
}

// Round 5
// 541.622 us; speedup vs baseline: 1.1327x; 1.1327x over previous
//
#include <hip/hip_runtime.h>

#define BATCH 4
#define T 8192
#define RES 256
#define SKIPC 512
#define NCLSC 256
#define NLAYERS 30
#define T0 5120
#define TBUF 3072
#define NT 64                 // tile width (cols) — 48 tiles x 4 batch = 192 blocks
#define STR 264               // LDS row stride in shorts (528 B): 2-way banks, 16B-aligned
#define HFSTR 260             // fp32 LDS row stride (dwords): stride%32=4 -> conflict-light
#define GRIDP 192             // 1 block/CU (131KB LDS) -> all blocks co-resident
#define MAXTILES 48

typedef __attribute__((ext_vector_type(8))) short short8x;   // 8 bf16
typedef __attribute__((ext_vector_type(4))) float floatx4;   // MFMA C/D
typedef unsigned short ushort_t;
typedef unsigned long long ull;

__device__ __forceinline__ ushort_t f2bf(float f) {
    unsigned u = __float_as_uint(f);
    u += 0x7fffu + ((u >> 16) & 1u);
    return (ushort_t)(u >> 16);
}
__device__ __forceinline__ float bf2f(ushort_t h) {
    return __uint_as_float(((unsigned)h) << 16);
}

// Coherent (cross-XCD) 8B access: relaxed agent-scope atomics -> sc1 ops, no
// cache-maintenance. Used ONLY for the tap0 halo (hbC) and flags.
__device__ __forceinline__ ull cload(const ull* p) {
    return __hip_atomic_load(p, __ATOMIC_RELAXED, __HIP_MEMORY_SCOPE_AGENT);
}
__device__ __forceinline__ void cstore(ull* p, ull v) {
    __hip_atomic_store(p, v, __ATOMIC_RELAXED, __HIP_MEMORY_SCOPE_AGENT);
}

#define WAITF(P) while (__hip_atomic_load((P), __ATOMIC_RELAXED, __HIP_MEMORY_SCOPE_AGENT) == 0) \
                     __builtin_amdgcn_s_sleep(1)

// Weight prep: Aswz/Rswz in exact MFMA A-fragment load order (coalesced loads).
// Layout depends only on (M=out-ch, K) — unchanged by the NT=64 retile.
__global__ __launch_bounds__(256) void prep_kernel(
    const float* __restrict__ Wd, const float* __restrict__ Wr,
    const float* __restrict__ Ws,
    ushort_t* __restrict__ Aswz, ushort_t* __restrict__ Rswz,
    ushort_t* __restrict__ WsT)
{
    long id = (long)blockIdx.x * 256 + threadIdx.x;
    const long R0 = 30L * 131072, R1 = 30L * 65536, R2 = 30L * 131072;
    if (id < R0) {
        long l = id >> 17; int r = (int)(id & 131071);
        int j = r & 7, lane = (r >> 3) & 63, f = (r >> 9) & 1, s = (r >> 10) & 15, wv = r >> 14;
        int row = wv * 32 + f * 16 + (lane & 15);
        int k = s * 32 + (lane >> 4) * 8 + j;
        int cin = k & 255, kk = k >> 8;
        Aswz[id] = f2bf(Wd[((l * 256 + row) * 256 + cin) * 2 + kk]);
        return;
    }
    id -= R0;
    if (id < R1) {
        long l = id >> 16; int r = (int)(id & 65535);
        int j = r & 7, lane = (r >> 3) & 63, f = (r >> 9) & 1, s = (r >> 10) & 7, wv = r >> 13;
        int row = wv * 32 + f * 16 + (lane & 15);
        int k = s * 32 + (lane >> 4) * 8 + j;
        Rswz[id] = f2bf(Wr[(l * 256 + row) * 256 + k]);
        return;
    }
    id -= R1;
    if (id < R2) {
        int o = (int)(id & 511); long rest = id >> 9; int cin = (int)(rest & 255); long l = rest >> 8;
        WsT[id] = f2bf(Ws[(l * 512 + o) * 256 + cin]);
    }
}

// h0[b][t][c] for t in [5120, 8191], fp32 + bf16 copies.
__global__ __launch_bounds__(256) void start_kernel(
    const float* __restrict__ x, const float* __restrict__ Wst,
    const float* __restrict__ bst, float* __restrict__ hf, ushort_t* __restrict__ hb)
{
    int id = blockIdx.x * 256 + threadIdx.x;
    int c = id & 255;
    int ti = (id >> 8) % TBUF;
    int b  = (id >> 8) / TBUF;
    int t = T0 + ti;
    float v = Wst[2 * c] * x[b * T + t - 1] + Wst[2 * c + 1] * x[b * T + t] + bst[c];
    hf[id] = v;
    hb[id] = f2bf(v);
}

// v5: LDS-RESIDENT activations. Each block owns one 64-col tile for all 30
// layers; hf(fp32)+hb(bf16) live in LDS (round-3 counters showed 358MB HBM
// writes = L2 thrash of the global activation ping-pong; that latency was the
// 30-hop chain cost). Per layer only weights (L2) + <=32KB coherent halo move.
// 192 blocks @ 1 block/CU (131KB LDS) -> co-resident -> flag waits safe.
__global__ __launch_bounds__(512, 2) void fused_layers_kernel(
    const float* __restrict__ hf,
    const ushort_t* __restrict__ hb0,
    const ushort_t* __restrict__ Asw,
    const float* __restrict__ bd,
    const ushort_t* __restrict__ Rsw,
    const float* __restrict__ br,
    float* __restrict__ gstore,
    ushort_t* __restrict__ hbC,
    int* __restrict__ flg)
{
    __shared__ __align__(16) ushort_t hbL[64 * STR];   // 33.8 KB: current h, bf16
    __shared__ __align__(16) ushort_t tp[64 * STR];    // 33.8 KB: tap0, then gated
    __shared__ __align__(16) float hfL[64 * HFSTR];    // 66.6 KB: current h, fp32

    const int tid = threadIdx.x;
    const int wv = tid >> 6, lane = tid & 63;
    const int quad = lane >> 4, l16 = lane & 15;
    const int mb = wv * 32;
    const int u0 = l16 * STR + quad * 8;
    const int u1 = u0 + 16 * STR;
    const int u2 = u0 + 32 * STR;
    const int u3 = u0 + 48 * STR;
    const int B = blockIdx.x;
    const int tile = B >> 2, b = B & 3;
    const int tb = 8192 - NT * (tile + 1);

    const float* __restrict__ hfg = hf + (size_t)b * TBUF * RES;
    const ushort_t* __restrict__ hbg = hb0 + (size_t)b * TBUF * RES;

    // Load tile-resident state: hfL (64KB) + hbL (32KB) from start buffers.
    #pragma unroll
    for (int p = 0; p < 8; ++p) {
        int c = p * 512 + tid;
        int row = c >> 6, q = (c & 63) * 4;
        float4 v = *(const float4*)(hfg + (size_t)(tb - T0 + row) * RES + q);
        *(float4*)&hfL[row * HFSTR + q] = v;
    }
    #pragma unroll
    for (int p = 0; p < 4; ++p) {
        int c = p * 512 + tid;
        int row = c >> 5, q = (c & 31) * 8;
        short8x v = *(const short8x*)(hbg + (size_t)(tb - T0 + row) * RES + q);
        *(short8x*)&hbL[row * STR + q] = v;
    }

    int rem = 3069;
    int ntiles_prev = 0;
    size_t cur_off = 0, prev_off = 0;

    for (int i = 0; i < NLAYERS; ++i) {
        const int dil = 1 << (i % 10);
        rem -= dil;                                    // rem[i+1]
        const int s_out = 8191 - rem;
        const int ntiles = (1 + rem + 63) >> 6;
        if (tile >= ntiles) break;                     // shrinking: done forever

        const ushort_t* __restrict__ aw =
            Asw + (size_t)i * (RES * 512) + (size_t)wv * 16384 + lane * 8;
        const ushort_t* __restrict__ rw =
            Rsw + (size_t)i * (RES * RES) + (size_t)wv * 8192 + lane * 8;
        const float* __restrict__ bdL = bd + i * RES;
        const float* __restrict__ brL = br + i * RES;

        // tap0 halo: rows [0, dil_eff) come from the single remote producer.
        const int dil_eff = dil < NT ? dil : NT;
        const int rdelta = dil < NT ? 1 : (dil >> 6);
        const int r = tile + rdelta;
        const bool remote_valid = (i > 0) && (r < ntiles_prev);
        const ushort_t* hbCp = nullptr;
        if (remote_valid)
            hbCp = hbC + prev_off + ((size_t)b * ntiles_prev + r) * (size_t)dil_eff * RES;

        __syncthreads();                 // prior-layer LDS readers done (incl. init)
        if (remote_valid && tid == 0)
            WAITF(flg + ((i - 1) * BATCH + b) * MAXTILES + r);
        __syncthreads();

        // Build tap0 (cols t-dil): own rows = shifted LDS copy from hbL;
        // remote rows from hbC (layer 0: from global start buffer);
        // missing producers leave stale rows -> those output cols are discarded.
        #pragma unroll
        for (int p = 0; p < 4; ++p) {
            int c = p * 512 + tid;
            int row = c >> 5, q = (c & 31) * 8;
            if (row >= dil_eff) {
                short8x v = *(const short8x*)&hbL[(row - dil) * STR + q];
                *(short8x*)&tp[row * STR + q] = v;
            } else if (i == 0) {
                int tt = tb + row - dil;
                tt = tt < T0 ? T0 : tt;                // clamped cols -> discarded
                short8x v = *(const short8x*)(hbg + (size_t)(tt - T0) * RES + q);
                *(short8x*)&tp[row * STR + q] = v;
            } else if (remote_valid) {
                const ull* src = (const ull*)(hbCp + (size_t)row * RES + q);
                ull v0 = cload(src), v1 = cload(src + 1);
                ull* dst = (ull*)&tp[row * STR + q];
                dst[0] = v0; dst[1] = v1;
            }
        }
        __syncthreads();

        // Conv GEMM: M=256, N=64, K=512 (s<8: tap0 = t-dil; s>=8: tap1 = hbL).
        floatx4 acc00, acc01, acc02, acc03, acc10, acc11, acc12, acc13;
        {
            float4 c0 = *(const float4*)(bdL + mb + quad * 4);
            float4 c1 = *(const float4*)(bdL + mb + 16 + quad * 4);
            acc00 = acc01 = acc02 = acc03 = (floatx4){c0.x, c0.y, c0.z, c0.w};
            acc10 = acc11 = acc12 = acc13 = (floatx4){c1.x, c1.y, c1.z, c1.w};
        }
        {
            short8x a0 = *(const short8x*)(aw);
            short8x a1 = *(const short8x*)(aw + 512);
            #pragma unroll
            for (int s = 0; s < 16; ++s) {
                short8x na0 = a0, na1 = a1;
                if (s < 15) {
                    na0 = *(const short8x*)(aw + (s + 1) * 1024);
                    na1 = *(const short8x*)(aw + (s + 1) * 1024 + 512);
                }
                const ushort_t* bb = (s < 8) ? tp : hbL;
                const int ko = (s & 7) * 32;
                short8x g0 = *(const short8x*)&bb[ko + u0];
                short8x g1 = *(const short8x*)&bb[ko + u1];
                short8x g2 = *(const short8x*)&bb[ko + u2];
                short8x g3 = *(const short8x*)&bb[ko + u3];
                acc00 = __builtin_amdgcn_mfma_f32_16x16x32_bf16(a0, g0, acc00, 0, 0, 0);
                acc10 = __builtin_amdgcn_mfma_f32_16x16x32_bf16(a1, g0, acc10, 0, 0, 0);
                acc01 = __builtin_amdgcn_mfma_f32_16x16x32_bf16(a0, g1, acc01, 0, 0, 0);
                acc11 = __builtin_amdgcn_mfma_f32_16x16x32_bf16(a1, g1, acc11, 0, 0, 0);
                acc02 = __builtin_amdgcn_mfma_f32_16x16x32_bf16(a0, g2, acc02, 0, 0, 0);
                acc12 = __builtin_amdgcn_mfma_f32_16x16x32_bf16(a1, g2, acc12, 0, 0, 0);
                acc03 = __builtin_amdgcn_mfma_f32_16x16x32_bf16(a0, g3, acc03, 0, 0, 0);
                acc13 = __builtin_amdgcn_mfma_f32_16x16x32_bf16(a1, g3, acc13, 0, 0, 0);
                a0 = na0; a1 = na1;
            }
        }
        __syncthreads();   // conv tap0 reads done before gate overlays tp

        // gate -> tp[n][cin]; capture t=8191 col fp32 for the skip path
        #define GATE(ACC, MF, NF) do {                                             \
            float gf[4]; ull pk = 0;                                               \
            _Pragma("unroll")                                                      \
            for (int rr = 0; rr < 4; ++rr) {                                       \
                float d = (ACC)[rr];                                               \
                float sig = 1.f / (1.f + __expf(-d));                              \
                float th = 1.f - 2.f / (__expf(2.f * d) + 1.f);                    \
                gf[rr] = th * sig;                                                 \
                pk |= ((ull)f2bf(gf[rr])) << (16 * rr);                            \
            }                                                                      \
            const int n = (NF) * 16 + l16;                                         \
            const int m = mb + (MF) * 16 + quad * 4;                               \
            *(ull*)&tp[n * STR + m] = pk;                                          \
            if (tile == 0 && n == 63) {                                            \
                float4 g4 = {gf[0], gf[1], gf[2], gf[3]};                          \
                *(float4*)&gstore[((size_t)i * BATCH + b) * RES + m] = g4;         \
            }                                                                      \
        } while (0)
        GATE(acc00, 0, 0); GATE(acc01, 0, 1); GATE(acc02, 0, 2); GATE(acc03, 0, 3);
        GATE(acc10, 1, 0); GATE(acc11, 1, 1); GATE(acc12, 1, 2); GATE(acc13, 1, 3);
        #undef GATE
        __syncthreads();

        // Residual GEMM: h' = h + Wr @ gated, K=256
        floatx4 r00, r01, r02, r03, r10, r11, r12, r13;
        {
            float4 c0 = *(const float4*)(brL + mb + quad * 4);
            float4 c1 = *(const float4*)(brL + mb + 16 + quad * 4);
            r00 = r01 = r02 = r03 = (floatx4){c0.x, c0.y, c0.z, c0.w};
            r10 = r11 = r12 = r13 = (floatx4){c1.x, c1.y, c1.z, c1.w};
        }
        {
            short8x a0 = *(const short8x*)(rw);
            short8x a1 = *(const short8x*)(rw + 512);
            #pragma unroll
            for (int s = 0; s < 8; ++s) {
                short8x na0 = a0, na1 = a1;
                if (s < 7) {
                    na0 = *(const short8x*)(rw + (s + 1) * 1024);
                    na1 = *(const short8x*)(rw + (s + 1) * 1024 + 512);
                }
                const int ko = s * 32;
                short8x g0 = *(const short8x*)&tp[ko + u0];
                short8x g1 = *(const short8x*)&tp[ko + u1];
                short8x g2 = *(const short8x*)&tp[ko + u2];
                short8x g3 = *(const short8x*)&tp[ko + u3];
                r00 = __builtin_amdgcn_mfma_f32_16x16x32_bf16(a0, g0, r00, 0, 0, 0);
                r10 = __builtin_amdgcn_mfma_f32_16x16x32_bf16(a1, g0, r10, 0, 0, 0);
                r01 = __builtin_amdgcn_mfma_f32_16x16x32_bf16(a0, g1, r01, 0, 0, 0);
                r11 = __builtin_amdgcn_mfma_f32_16x16x32_bf16(a1, g1, r11, 0, 0, 0);
                r02 = __builtin_amdgcn_mfma_f32_16x16x32_bf16(a0, g2, r02, 0, 0, 0);
                r12 = __builtin_amdgcn_mfma_f32_16x16x32_bf16(a1, g2, r12, 0, 0, 0);
                r03 = __builtin_amdgcn_mfma_f32_16x16x32_bf16(a0, g3, r03, 0, 0, 0);
                r13 = __builtin_amdgcn_mfma_f32_16x16x32_bf16(a1, g3, r13, 0, 0, 0);
                a0 = na0; a1 = na1;
            }
        }

        // Epilogue: fp32 residual RMW + bf16 copy, entirely in LDS; valid cols only.
        #define EPI(NF, RA, RB) do {                                               \
            const int t = tb + (NF) * 16 + l16;                                    \
            if (t >= s_out) {                                                      \
                const int n = (NF) * 16 + l16;                                     \
                {                                                                  \
                    const int m = mb + quad * 4;                                   \
                    float4 ho = *(const float4*)&hfL[n * HFSTR + m];               \
                    float4 hn = {ho.x + (RA)[0], ho.y + (RA)[1],                   \
                                 ho.z + (RA)[2], ho.w + (RA)[3]};                  \
                    *(float4*)&hfL[n * HFSTR + m] = hn;                            \
                    ull pk = (ull)f2bf(hn.x) | ((ull)f2bf(hn.y) << 16)             \
                           | ((ull)f2bf(hn.z) << 32) | ((ull)f2bf(hn.w) << 48);    \
                    *(ull*)&hbL[n * STR + m] = pk;                                 \
                }                                                                  \
                {                                                                  \
                    const int m = mb + 16 + quad * 4;                              \
                    float4 ho = *(const float4*)&hfL[n * HFSTR + m];               \
                    float4 hn = {ho.x + (RB)[0], ho.y + (RB)[1],                   \
                                 ho.z + (RB)[2], ho.w + (RB)[3]};                  \
                    *(float4*)&hfL[n * HFSTR + m] = hn;                            \
                    ull pk = (ull)f2bf(hn.x) | ((ull)f2bf(hn.y) << 16)             \
                           | ((ull)f2bf(hn.z) << 32) | ((ull)f2bf(hn.w) << 48);    \
                    *(ull*)&hbL[n * STR + m] = pk;                                 \
                }                                                                  \
            }                                                                      \
        } while (0)
        EPI(0, r00, r10); EPI(1, r01, r11); EPI(2, r02, r12); EPI(3, r03, r13);
        #undef EPI
        __syncthreads();   // hbL fully updated before publish reads

        // Publish the high Ci cols to hbC (coherent) + ready flag.
        const int dnext = (i < NLAYERS - 1) ? (1 << ((i + 1) % 10)) : 0;
        const int Ci = dnext < NT ? dnext : NT;
        const int rdn = (dnext < NT) ? 1 : (dnext >> 6);
        if (Ci > 0 && tile >= rdn) {
            ushort_t* hbCc = hbC + cur_off + ((size_t)b * ntiles + tile) * (size_t)Ci * RES;
            for (int c = tid; c < Ci * 32; c += 512) {
                int row = (NT - Ci) + (c >> 5), q = (c & 31) * 8;
                const ull* src = (const ull*)&hbL[row * STR + q];
                ull v0 = src[0], v1 = src[1];
                ull* dst = (ull*)(hbCc + (size_t)(c >> 5) * RES + q);
                cstore(dst, v0); cstore(dst + 1, v1);
            }
        }
        asm volatile("s_waitcnt vmcnt(0)" ::: "memory");
        __syncthreads();
        if (tid == 0)
            __hip_atomic_store(flg + ((size_t)i * BATCH + b) * MAXTILES + tile, 1,
                               __ATOMIC_RELAXED, __HIP_MEMORY_SCOPE_AGENT);

        ntiles_prev = ntiles;
        prev_off = cur_off;
        cur_off += (size_t)BATCH * ntiles * Ci * RES;
    }
}

// All 30 skip matvecs in parallel: block (l,b), thread o
__global__ __launch_bounds__(512) void skip_kernel(
    const ushort_t* __restrict__ WsT, const float* __restrict__ bs,
    const float* __restrict__ gstore, float* __restrict__ skip)
{
    const int l = blockIdx.x, b = blockIdx.y, o = threadIdx.x;
    const ushort_t* w = WsT + (size_t)l * 131072;
    const float* g = gstore + (size_t)(l * BATCH + b) * RES;
    float a = bs[l * SKIPC + o];
    #pragma unroll 4
    for (int cin = 0; cin < RES; ++cin)
        a = fmaf(bf2f(w[cin * SKIPC + o]), g[cin], a);
    atomicAdd(&skip[b * SKIPC + o], a);
}

// e1[b][o] = relu(W1 @ relu(skip[b]) + b1); grid (B, 16), block computes 32 outputs
__global__ __launch_bounds__(256) void end1_kernel(
    const float* __restrict__ skip, const float* __restrict__ W1,
    const float* __restrict__ b1, float* __restrict__ e1ws)
{
    __shared__ float s[SKIPC];
    __shared__ float part[256];
    const int b = blockIdx.x, og = blockIdx.y, tid = threadIdx.x;
    s[tid]       = fmaxf(skip[b * SKIPC + tid], 0.f);
    s[tid + 256] = fmaxf(skip[b * SKIPC + tid + 256], 0.f);
    __syncthreads();
    const int o_l = tid >> 3, kp = tid & 7;
    const int o = og * 32 + o_l;
    const float* w = W1 + (size_t)o * SKIPC + kp * 64;
    const float* sp = s + kp * 64;
    float a = 0.f;
    #pragma unroll 8
    for (int j = 0; j < 64; ++j) a = fmaf(w[j], sp[j], a);
    part[tid] = a;
    __syncthreads();
    if (tid < 32) {
        float r = b1[og * 32 + tid];
        #pragma unroll
        for (int k = 0; k < 8; ++k) r += part[tid * 8 + k];
        e1ws[b * SKIPC + og * 32 + tid] = fmaxf(r, 0.f);
    }
}

// out[b][cls] = W2 @ e1 + b2; grid (B, 8), block computes 32 outputs
__global__ __launch_bounds__(256) void end2_kernel(
    const float* __restrict__ e1ws, const float* __restrict__ W2,
    const float* __restrict__ b2, float* __restrict__ out)
{
    __shared__ float e[SKIPC];
    __shared__ float part[256];
    const int b = blockIdx.x, og = blockIdx.y, tid = threadIdx.x;
    e[tid]       = e1ws[b * SKIPC + tid];
    e[tid + 256] = e1ws[b * SKIPC + tid + 256];
    __syncthreads();
    const int o_l = tid >> 3, kp = tid & 7;
    const int cls = og * 32 + o_l;
    const float* w = W2 + (size_t)cls * SKIPC + kp * 64;
    const float* ep = e + kp * 64;
    float a = 0.f;
    #pragma unroll 8
    for (int j = 0; j < 64; ++j) a = fmaf(w[j], ep[j], a);
    part[tid] = a;
    __syncthreads();
    if (tid < 32) {
        float r = b2[og * 32 + tid];
        #pragma unroll
        for (int k = 0; k < 8; ++k) r += part[tid * 8 + k];
        out[b * NCLSC + og * 32 + tid] = r;
    }
}

extern "C" void kernel_launch(void* const* d_in, const int* in_sizes, int n_in,
                              void* d_out, int out_size, void* d_ws, size_t ws_size,
                              hipStream_t stream)
{
    const float* x   = (const float*)d_in[0];
    const float* Wst = (const float*)d_in[1];
    const float* bst = (const float*)d_in[2];
    const float* Wd  = (const float*)d_in[3];
    const float* bd  = (const float*)d_in[4];
    const float* Wr  = (const float*)d_in[5];
    const float* br  = (const float*)d_in[6];
    const float* Ws  = (const float*)d_in[7];
    const float* bs  = (const float*)d_in[8];
    const float* W1  = (const float*)d_in[9];
    const float* b1  = (const float*)d_in[10];
    const float* W2  = (const float*)d_in[11];
    const float* b2  = (const float*)d_in[12];
    float* out = (float*)d_out;

    // hbC size: per layer, BATCH * ntiles * Ci cols of 256 bf16 (Ci = min(dil_next,64))
    size_t hbC_shorts = 0;
    {
        int rem = 3069;
        for (int i = 0; i < NLAYERS; ++i) {
            int d = 1 << (i % 10);
            rem -= d;
            int ntl = (1 + rem + 63) >> 6;
            int dn = (i < NLAYERS - 1) ? (1 << ((i + 1) % 10)) : 0;
            int Ci = (dn < NT) ? dn : NT;
            hbC_shorts += (size_t)BATCH * ntl * Ci * RES;
        }
    }

    char* w = (char*)d_ws;
    float* hf     = (float*)w;     w += (size_t)BATCH * TBUF * RES * 4;
    ushort_t* hb0 = (ushort_t*)w;  w += (size_t)BATCH * TBUF * RES * 2;
    ushort_t* Asw = (ushort_t*)w;  w += (size_t)NLAYERS * RES * 512 * 2;
    ushort_t* Rsw = (ushort_t*)w;  w += (size_t)NLAYERS * RES * RES * 2;
    ushort_t* WsT = (ushort_t*)w;  w += (size_t)NLAYERS * RES * SKIPC * 2;
    float* gstore = (float*)w;     w += (size_t)NLAYERS * BATCH * RES * 4;
    float* skip   = (float*)w;     w += (size_t)BATCH * SKIPC * 4;
    float* e1ws   = (float*)w;     w += (size_t)BATCH * SKIPC * 4;
    ushort_t* hbC = (ushort_t*)w;  w += hbC_shorts * 2;
    int* flg      = (int*)w;       w += (size_t)NLAYERS * BATCH * MAXTILES * 4;

    prep_kernel<<<38400, 256, 0, stream>>>(Wd, Wr, Ws, Asw, Rsw, WsT);
    start_kernel<<<(BATCH * TBUF * RES) / 256, 256, 0, stream>>>(x, Wst, bst, hf, hb0);
    hipMemsetAsync(skip, 0, BATCH * SKIPC * 4, stream);
    hipMemsetAsync(flg, 0, (size_t)NLAYERS * BATCH * MAXTILES * 4, stream);

    fused_layers_kernel<<<GRIDP, 512, 0, stream>>>(
        hf, hb0, Asw, bd, Rsw, br, gstore, hbC, flg);

    skip_kernel<<<dim3(NLAYERS, BATCH), 512, 0, stream>>>(WsT, bs, gstore, skip);
    end1_kernel<<<dim3(BATCH, 16), 256, 0, stream>>>(skip, W1, b1, e1ws);
    end2_kernel<<<dim3(BATCH, 8), 256, 0, stream>>>(e1ws, W2, b2, out);
}

// Round 6
// 539.637 us; speedup vs baseline: 1.1369x; 1.0037x over previous
//
#include <hip/hip_runtime.h>

#define BATCH 4
#define T 8192
#define RES 256
#define SKIPC 512
#define NCLSC 256
#define NLAYERS 30
#define T0 5120
#define TBUF 3072
#define NT 64                 // tile width (cols) — 48 tiles x 4 batch = 192 blocks
#define STR 264               // LDS row stride in shorts (528 B): 2-way banks, 16B-aligned
#define HFSTR 260             // fp32 LDS row stride (dwords): stride%32=4 -> conflict-light
#define GRIDP 192             // 1 block/CU (131KB LDS) -> all blocks co-resident
#define MAXTILES 48

typedef __attribute__((ext_vector_type(8))) short short8x;   // 8 bf16
typedef __attribute__((ext_vector_type(4))) float floatx4;   // MFMA C/D
typedef unsigned short ushort_t;
typedef unsigned long long ull;

__device__ __forceinline__ ushort_t f2bf(float f) {
    unsigned u = __float_as_uint(f);
    u += 0x7fffu + ((u >> 16) & 1u);
    return (ushort_t)(u >> 16);
}
__device__ __forceinline__ float bf2f(ushort_t h) {
    return __uint_as_float(((unsigned)h) << 16);
}

// Coherent (cross-XCD) 8B access: relaxed agent-scope atomics -> sc1 ops, no
// cache-maintenance. Used ONLY for the tap0 halo (hbC) and flags.
__device__ __forceinline__ ull cload(const ull* p) {
    return __hip_atomic_load(p, __ATOMIC_RELAXED, __HIP_MEMORY_SCOPE_AGENT);
}
__device__ __forceinline__ void cstore(ull* p, ull v) {
    __hip_atomic_store(p, v, __ATOMIC_RELAXED, __HIP_MEMORY_SCOPE_AGENT);
}

#define WAITF(P) while (__hip_atomic_load((P), __ATOMIC_RELAXED, __HIP_MEMORY_SCOPE_AGENT) == 0) \
                     __builtin_amdgcn_s_sleep(1)

#define MFMA __builtin_amdgcn_mfma_f32_16x16x32_bf16

// Weight prep: Aswz/Rswz in exact MFMA A-fragment load order (coalesced loads).
__global__ __launch_bounds__(256) void prep_kernel(
    const float* __restrict__ Wd, const float* __restrict__ Wr,
    const float* __restrict__ Ws,
    ushort_t* __restrict__ Aswz, ushort_t* __restrict__ Rswz,
    ushort_t* __restrict__ WsT)
{
    long id = (long)blockIdx.x * 256 + threadIdx.x;
    const long R0 = 30L * 131072, R1 = 30L * 65536, R2 = 30L * 131072;
    if (id < R0) {
        long l = id >> 17; int r = (int)(id & 131071);
        int j = r & 7, lane = (r >> 3) & 63, f = (r >> 9) & 1, s = (r >> 10) & 15, wv = r >> 14;
        int row = wv * 32 + f * 16 + (lane & 15);
        int k = s * 32 + (lane >> 4) * 8 + j;
        int cin = k & 255, kk = k >> 8;
        Aswz[id] = f2bf(Wd[((l * 256 + row) * 256 + cin) * 2 + kk]);
        return;
    }
    id -= R0;
    if (id < R1) {
        long l = id >> 16; int r = (int)(id & 65535);
        int j = r & 7, lane = (r >> 3) & 63, f = (r >> 9) & 1, s = (r >> 10) & 7, wv = r >> 13;
        int row = wv * 32 + f * 16 + (lane & 15);
        int k = s * 32 + (lane >> 4) * 8 + j;
        Rswz[id] = f2bf(Wr[(l * 256 + row) * 256 + k]);
        return;
    }
    id -= R1;
    if (id < R2) {
        int o = (int)(id & 511); long rest = id >> 9; int cin = (int)(rest & 255); long l = rest >> 8;
        WsT[id] = f2bf(Ws[(l * 512 + o) * 256 + cin]);
    }
}

// h0[b][t][c] for t in [5120, 8191], fp32 + bf16 copies.
__global__ __launch_bounds__(256) void start_kernel(
    const float* __restrict__ x, const float* __restrict__ Wst,
    const float* __restrict__ bst, float* __restrict__ hf, ushort_t* __restrict__ hb)
{
    int id = blockIdx.x * 256 + threadIdx.x;
    int c = id & 255;
    int ti = (id >> 8) % TBUF;
    int b  = (id >> 8) / TBUF;
    int t = T0 + ti;
    float v = Wst[2 * c] * x[b * T + t - 1] + Wst[2 * c + 1] * x[b * T + t] + bst[c];
    hf[id] = v;
    hb[id] = f2bf(v);
}

// v6 = v5 (LDS-resident activations) + latency-chain surgery:
//  - 4-deep ROLLING weight-fragment prefetch (compile-time rotated window;
//    v4's burst-16 thrashed L2 and hit the 128-VGPR cap, here cap=256)
//  - conv reordered tap1-half first; flag wait + remote halo staging sit
//    between the halves, hidden under 64 MFMAs; tap0 weights prefetched
//    during the tap1 half, res weights during the gate phase
//  - B-fragments (LDS) prefetched 1 step ahead in all GEMM loops
__global__ __launch_bounds__(512, 2) void fused_layers_kernel(
    const float* __restrict__ hf,
    const ushort_t* __restrict__ hb0,
    const ushort_t* __restrict__ Asw,
    const float* __restrict__ bd,
    const ushort_t* __restrict__ Rsw,
    const float* __restrict__ br,
    float* __restrict__ gstore,
    ushort_t* __restrict__ hbC,
    int* __restrict__ flg)
{
    __shared__ __align__(16) ushort_t hbL[64 * STR];   // 33.8 KB: current h, bf16
    __shared__ __align__(16) ushort_t tp[64 * STR];    // 33.8 KB: tap0, then gated
    __shared__ __align__(16) float hfL[64 * HFSTR];    // 66.6 KB: current h, fp32

    const int tid = threadIdx.x;
    const int wv = tid >> 6, lane = tid & 63;
    const int quad = lane >> 4, l16 = lane & 15;
    const int mb = wv * 32;
    const int u0 = l16 * STR + quad * 8;
    const int u1 = u0 + 16 * STR;
    const int u2 = u0 + 32 * STR;
    const int u3 = u0 + 48 * STR;
    const int B = blockIdx.x;
    const int tile = B >> 2, b = B & 3;
    const int tb = 8192 - NT * (tile + 1);

    const float* __restrict__ hfg = hf + (size_t)b * TBUF * RES;
    const ushort_t* __restrict__ hbg = hb0 + (size_t)b * TBUF * RES;

    // Load tile-resident state: hfL (64KB) + hbL (32KB) from start buffers.
    #pragma unroll
    for (int p = 0; p < 8; ++p) {
        int c = p * 512 + tid;
        int row = c >> 6, q = (c & 63) * 4;
        float4 v = *(const float4*)(hfg + (size_t)(tb - T0 + row) * RES + q);
        *(float4*)&hfL[row * HFSTR + q] = v;
    }
    #pragma unroll
    for (int p = 0; p < 4; ++p) {
        int c = p * 512 + tid;
        int row = c >> 5, q = (c & 31) * 8;
        short8x v = *(const short8x*)(hbg + (size_t)(tb - T0 + row) * RES + q);
        *(short8x*)&hbL[row * STR + q] = v;
    }
    __syncthreads();   // init visible to all waves before layer 0

    int rem = 3069;
    int ntiles_prev = 0;
    size_t cur_off = 0, prev_off = 0;

    for (int i = 0; i < NLAYERS; ++i) {
        const int dil = 1 << (i % 10);
        rem -= dil;                                    // rem[i+1]
        const int s_out = 8191 - rem;
        const int ntiles = (1 + rem + 63) >> 6;
        if (tile >= ntiles) break;                     // shrinking: done forever

        const ushort_t* __restrict__ aw =
            Asw + (size_t)i * (RES * 512) + (size_t)wv * 16384 + lane * 8;
        const ushort_t* __restrict__ rw =
            Rsw + (size_t)i * (RES * RES) + (size_t)wv * 8192 + lane * 8;
        const float* __restrict__ bdL = bd + i * RES;
        const float* __restrict__ brL = br + i * RES;

        // tap0 halo: rows [0, dil_eff) come from the single remote producer.
        const int dil_eff = dil < NT ? dil : NT;
        const int rdelta = dil < NT ? 1 : (dil >> 6);
        const int r = tile + rdelta;
        const bool remote_valid = (i > 0) && (r < ntiles_prev);
        const ushort_t* hbCp = nullptr;
        if (remote_valid)
            hbCp = hbC + prev_off + ((size_t)b * ntiles_prev + r) * (size_t)dil_eff * RES;

        // (no sync needed here: prev layer's S6/S7 ordered all tp/hbL hazards)

        // Build tap0 OWN rows (row >= dil_eff): shifted copy from hbL.
        #pragma unroll
        for (int p = 0; p < 4; ++p) {
            int c = p * 512 + tid;
            int row = c >> 5, q = (c & 31) * 8;
            if (row >= dil_eff) {
                short8x v = *(const short8x*)&hbL[(row - dil) * STR + q];
                *(short8x*)&tp[row * STR + q] = v;
            }
        }

        floatx4 acc00, acc01, acc02, acc03, acc10, acc11, acc12, acc13;
        {
            float4 c0 = *(const float4*)(bdL + mb + quad * 4);
            float4 c1 = *(const float4*)(bdL + mb + 16 + quad * 4);
            acc00 = acc01 = acc02 = acc03 = (floatx4){c0.x, c0.y, c0.z, c0.w};
            acc10 = acc11 = acc12 = acc13 = (floatx4){c1.x, c1.y, c1.z, c1.w};
        }

        // ---- Conv, tap1 half first (reads hbL only; no remote dependency).
        // Rolling 4-deep weight window; during s>=4 we already prefetch the
        // tap0 half's first 4 weight pairs (they fly across the flag wait).
        short8x Aw0[4], Aw1[4];
        #pragma unroll
        for (int s = 0; s < 4; ++s) {
            Aw0[s] = *(const short8x*)(aw + (8 + s) * 1024);
            Aw1[s] = *(const short8x*)(aw + (8 + s) * 1024 + 512);
        }
        {
            short8x g0 = *(const short8x*)&hbL[u0];
            short8x g1 = *(const short8x*)&hbL[u1];
            short8x g2 = *(const short8x*)&hbL[u2];
            short8x g3 = *(const short8x*)&hbL[u3];
            #pragma unroll
            for (int s = 0; s < 8; ++s) {
                short8x a0 = Aw0[s & 3], a1 = Aw1[s & 3];
                if (s < 4) {
                    Aw0[s & 3] = *(const short8x*)(aw + (12 + s) * 1024);
                    Aw1[s & 3] = *(const short8x*)(aw + (12 + s) * 1024 + 512);
                } else {
                    Aw0[s & 3] = *(const short8x*)(aw + (s - 4) * 1024);
                    Aw1[s & 3] = *(const short8x*)(aw + (s - 4) * 1024 + 512);
                }
                short8x n0 = g0, n1 = g1, n2 = g2, n3 = g3;
                if (s < 7) {
                    const int ko = (s + 1) * 32;
                    n0 = *(const short8x*)&hbL[ko + u0];
                    n1 = *(const short8x*)&hbL[ko + u1];
                    n2 = *(const short8x*)&hbL[ko + u2];
                    n3 = *(const short8x*)&hbL[ko + u3];
                }
                acc00 = MFMA(a0, g0, acc00, 0, 0, 0);
                acc10 = MFMA(a1, g0, acc10, 0, 0, 0);
                acc01 = MFMA(a0, g1, acc01, 0, 0, 0);
                acc11 = MFMA(a1, g1, acc11, 0, 0, 0);
                acc02 = MFMA(a0, g2, acc02, 0, 0, 0);
                acc12 = MFMA(a1, g2, acc12, 0, 0, 0);
                acc03 = MFMA(a0, g3, acc03, 0, 0, 0);
                acc13 = MFMA(a1, g3, acc13, 0, 0, 0);
                g0 = n0; g1 = n1; g2 = n2; g3 = n3;
            }
        }

        // ---- Flag wait + remote/l0 halo staging (rows < dil_eff) ----
        if (remote_valid) {
            if (tid == 0) WAITF(flg + ((i - 1) * BATCH + b) * MAXTILES + r);
            __syncthreads();                                          // S2
        }
        if (i == 0) {
            #pragma unroll
            for (int p = 0; p < 4; ++p) {
                int c = p * 512 + tid;
                int row = c >> 5, q = (c & 31) * 8;
                if (row < dil_eff) {
                    int tt = tb + row - dil;
                    tt = tt < T0 ? T0 : tt;            // clamped cols -> discarded
                    short8x v = *(const short8x*)(hbg + (size_t)(tt - T0) * RES + q);
                    *(short8x*)&tp[row * STR + q] = v;
                }
            }
        } else if (remote_valid) {
            #pragma unroll
            for (int p = 0; p < 4; ++p) {
                int c = p * 512 + tid;
                int row = c >> 5, q = (c & 31) * 8;
                if (row < dil_eff) {
                    const ull* src = (const ull*)(hbCp + (size_t)row * RES + q);
                    ull v0 = cload(src), v1 = cload(src + 1);
                    ull* dst = (ull*)&tp[row * STR + q];
                    dst[0] = v0; dst[1] = v1;
                }
            }
        }
        __syncthreads();                                              // S3

        // ---- Conv, tap0 half (reads tp). First 4 weight pairs already in Aw.
        {
            short8x g0 = *(const short8x*)&tp[u0];
            short8x g1 = *(const short8x*)&tp[u1];
            short8x g2 = *(const short8x*)&tp[u2];
            short8x g3 = *(const short8x*)&tp[u3];
            #pragma unroll
            for (int s = 0; s < 8; ++s) {
                short8x a0 = Aw0[s & 3], a1 = Aw1[s & 3];
                if (s < 4) {
                    Aw0[s & 3] = *(const short8x*)(aw + (s + 4) * 1024);
                    Aw1[s & 3] = *(const short8x*)(aw + (s + 4) * 1024 + 512);
                }
                short8x n0 = g0, n1 = g1, n2 = g2, n3 = g3;
                if (s < 7) {
                    const int ko = (s + 1) * 32;
                    n0 = *(const short8x*)&tp[ko + u0];
                    n1 = *(const short8x*)&tp[ko + u1];
                    n2 = *(const short8x*)&tp[ko + u2];
                    n3 = *(const short8x*)&tp[ko + u3];
                }
                acc00 = MFMA(a0, g0, acc00, 0, 0, 0);
                acc10 = MFMA(a1, g0, acc10, 0, 0, 0);
                acc01 = MFMA(a0, g1, acc01, 0, 0, 0);
                acc11 = MFMA(a1, g1, acc11, 0, 0, 0);
                acc02 = MFMA(a0, g2, acc02, 0, 0, 0);
                acc12 = MFMA(a1, g2, acc12, 0, 0, 0);
                acc03 = MFMA(a0, g3, acc03, 0, 0, 0);
                acc13 = MFMA(a1, g3, acc13, 0, 0, 0);
                g0 = n0; g1 = n1; g2 = n2; g3 = n3;
            }
        }

        // Res weights: first 4 pairs issued now -> fly under the gate VALU phase.
        short8x Rw0[4], Rw1[4];
        #pragma unroll
        for (int s = 0; s < 4; ++s) {
            Rw0[s] = *(const short8x*)(rw + s * 1024);
            Rw1[s] = *(const short8x*)(rw + s * 1024 + 512);
        }
        __syncthreads();   // S4: conv tp reads done before gate overlays tp

        // gate -> tp[n][cin]; capture t=8191 col fp32 for the skip path
        #define GATE(ACC, MF, NF) do {                                             \
            float gf[4]; ull pk = 0;                                               \
            _Pragma("unroll")                                                      \
            for (int rr = 0; rr < 4; ++rr) {                                       \
                float d = (ACC)[rr];                                               \
                float sig = 1.f / (1.f + __expf(-d));                              \
                float th = 1.f - 2.f / (__expf(2.f * d) + 1.f);                    \
                gf[rr] = th * sig;                                                 \
                pk |= ((ull)f2bf(gf[rr])) << (16 * rr);                            \
            }                                                                      \
            const int n = (NF) * 16 + l16;                                         \
            const int m = mb + (MF) * 16 + quad * 4;                               \
            *(ull*)&tp[n * STR + m] = pk;                                          \
            if (tile == 0 && n == 63) {                                            \
                float4 g4 = {gf[0], gf[1], gf[2], gf[3]};                          \
                *(float4*)&gstore[((size_t)i * BATCH + b) * RES + m] = g4;         \
            }                                                                      \
        } while (0)
        GATE(acc00, 0, 0); GATE(acc01, 0, 1); GATE(acc02, 0, 2); GATE(acc03, 0, 3);
        GATE(acc10, 1, 0); GATE(acc11, 1, 1); GATE(acc12, 1, 2); GATE(acc13, 1, 3);
        #undef GATE
        __syncthreads();   // S5

        // Residual GEMM: h' = h + Wr @ gated, K=256; rolling 4-deep window.
        floatx4 r00, r01, r02, r03, r10, r11, r12, r13;
        {
            float4 c0 = *(const float4*)(brL + mb + quad * 4);
            float4 c1 = *(const float4*)(brL + mb + 16 + quad * 4);
            r00 = r01 = r02 = r03 = (floatx4){c0.x, c0.y, c0.z, c0.w};
            r10 = r11 = r12 = r13 = (floatx4){c1.x, c1.y, c1.z, c1.w};
        }
        {
            short8x g0 = *(const short8x*)&tp[u0];
            short8x g1 = *(const short8x*)&tp[u1];
            short8x g2 = *(const short8x*)&tp[u2];
            short8x g3 = *(const short8x*)&tp[u3];
            #pragma unroll
            for (int s = 0; s < 8; ++s) {
                short8x a0 = Rw0[s & 3], a1 = Rw1[s & 3];
                if (s < 4) {
                    Rw0[s & 3] = *(const short8x*)(rw + (s + 4) * 1024);
                    Rw1[s & 3] = *(const short8x*)(rw + (s + 4) * 1024 + 512);
                }
                short8x n0 = g0, n1 = g1, n2 = g2, n3 = g3;
                if (s < 7) {
                    const int ko = (s + 1) * 32;
                    n0 = *(const short8x*)&tp[ko + u0];
                    n1 = *(const short8x*)&tp[ko + u1];
                    n2 = *(const short8x*)&tp[ko + u2];
                    n3 = *(const short8x*)&tp[ko + u3];
                }
                r00 = MFMA(a0, g0, r00, 0, 0, 0);
                r10 = MFMA(a1, g0, r10, 0, 0, 0);
                r01 = MFMA(a0, g1, r01, 0, 0, 0);
                r11 = MFMA(a1, g1, r11, 0, 0, 0);
                r02 = MFMA(a0, g2, r02, 0, 0, 0);
                r12 = MFMA(a1, g2, r12, 0, 0, 0);
                r03 = MFMA(a0, g3, r03, 0, 0, 0);
                r13 = MFMA(a1, g3, r13, 0, 0, 0);
                g0 = n0; g1 = n1; g2 = n2; g3 = n3;
            }
        }

        // Epilogue: fp32 residual RMW + bf16 copy, entirely in LDS; valid cols only.
        #define EPI(NF, RA, RB) do {                                               \
            const int t = tb + (NF) * 16 + l16;                                    \
            if (t >= s_out) {                                                      \
                const int n = (NF) * 16 + l16;                                     \
                {                                                                  \
                    const int m = mb + quad * 4;                                   \
                    float4 ho = *(const float4*)&hfL[n * HFSTR + m];               \
                    float4 hn = {ho.x + (RA)[0], ho.y + (RA)[1],                   \
                                 ho.z + (RA)[2], ho.w + (RA)[3]};                  \
                    *(float4*)&hfL[n * HFSTR + m] = hn;                            \
                    ull pk = (ull)f2bf(hn.x) | ((ull)f2bf(hn.y) << 16)             \
                           | ((ull)f2bf(hn.z) << 32) | ((ull)f2bf(hn.w) << 48);    \
                    *(ull*)&hbL[n * STR + m] = pk;                                 \
                }                                                                  \
                {                                                                  \
                    const int m = mb + 16 + quad * 4;                              \
                    float4 ho = *(const float4*)&hfL[n * HFSTR + m];               \
                    float4 hn = {ho.x + (RB)[0], ho.y + (RB)[1],                   \
                                 ho.z + (RB)[2], ho.w + (RB)[3]};                  \
                    *(float4*)&hfL[n * HFSTR + m] = hn;                            \
                    ull pk = (ull)f2bf(hn.x) | ((ull)f2bf(hn.y) << 16)             \
                           | ((ull)f2bf(hn.z) << 32) | ((ull)f2bf(hn.w) << 48);    \
                    *(ull*)&hbL[n * STR + m] = pk;                                 \
                }                                                                  \
            }                                                                      \
        } while (0)
        EPI(0, r00, r10); EPI(1, r01, r11); EPI(2, r02, r12); EPI(3, r03, r13);
        #undef EPI
        __syncthreads();   // S6: hbL fully updated before publish reads

        // Publish the high Ci cols to hbC (coherent) + ready flag.
        const int dnext = (i < NLAYERS - 1) ? (1 << ((i + 1) % 10)) : 0;
        const int Ci = dnext < NT ? dnext : NT;
        const int rdn = (dnext < NT) ? 1 : (dnext >> 6);
        if (Ci > 0 && tile >= rdn) {
            ushort_t* hbCc = hbC + cur_off + ((size_t)b * ntiles + tile) * (size_t)Ci * RES;
            for (int c = tid; c < Ci * 32; c += 512) {
                int row = (NT - Ci) + (c >> 5), q = (c & 31) * 8;
                const ull* src = (const ull*)&hbL[row * STR + q];
                ull v0 = src[0], v1 = src[1];
                ull* dst = (ull*)(hbCc + (size_t)(c >> 5) * RES + q);
                cstore(dst, v0); cstore(dst + 1, v1);
            }
        }
        asm volatile("s_waitcnt vmcnt(0)" ::: "memory");
        __syncthreads();   // S7
        if (tid == 0)
            __hip_atomic_store(flg + ((size_t)i * BATCH + b) * MAXTILES + tile, 1,
                               __ATOMIC_RELAXED, __HIP_MEMORY_SCOPE_AGENT);

        ntiles_prev = ntiles;
        prev_off = cur_off;
        cur_off += (size_t)BATCH * ntiles * Ci * RES;
    }
}

// All 30 skip matvecs in parallel: block (l,b), thread o
__global__ __launch_bounds__(512) void skip_kernel(
    const ushort_t* __restrict__ WsT, const float* __restrict__ bs,
    const float* __restrict__ gstore, float* __restrict__ skip)
{
    const int l = blockIdx.x, b = blockIdx.y, o = threadIdx.x;
    const ushort_t* w = WsT + (size_t)l * 131072;
    const float* g = gstore + (size_t)(l * BATCH + b) * RES;
    float a = bs[l * SKIPC + o];
    #pragma unroll 4
    for (int cin = 0; cin < RES; ++cin)
        a = fmaf(bf2f(w[cin * SKIPC + o]), g[cin], a);
    atomicAdd(&skip[b * SKIPC + o], a);
}

// e1[b][o] = relu(W1 @ relu(skip[b]) + b1); grid (B, 16), block computes 32 outputs
__global__ __launch_bounds__(256) void end1_kernel(
    const float* __restrict__ skip, const float* __restrict__ W1,
    const float* __restrict__ b1, float* __restrict__ e1ws)
{
    __shared__ float s[SKIPC];
    __shared__ float part[256];
    const int b = blockIdx.x, og = blockIdx.y, tid = threadIdx.x;
    s[tid]       = fmaxf(skip[b * SKIPC + tid], 0.f);
    s[tid + 256] = fmaxf(skip[b * SKIPC + tid + 256], 0.f);
    __syncthreads();
    const int o_l = tid >> 3, kp = tid & 7;
    const int o = og * 32 + o_l;
    const float* w = W1 + (size_t)o * SKIPC + kp * 64;
    const float* sp = s + kp * 64;
    float a = 0.f;
    #pragma unroll 8
    for (int j = 0; j < 64; ++j) a = fmaf(w[j], sp[j], a);
    part[tid] = a;
    __syncthreads();
    if (tid < 32) {
        float r = b1[og * 32 + tid];
        #pragma unroll
        for (int k = 0; k < 8; ++k) r += part[tid * 8 + k];
        e1ws[b * SKIPC + og * 32 + tid] = fmaxf(r, 0.f);
    }
}

// out[b][cls] = W2 @ e1 + b2; grid (B, 8), block computes 32 outputs
__global__ __launch_bounds__(256) void end2_kernel(
    const float* __restrict__ e1ws, const float* __restrict__ W2,
    const float* __restrict__ b2, float* __restrict__ out)
{
    __shared__ float e[SKIPC];
    __shared__ float part[256];
    const int b = blockIdx.x, og = blockIdx.y, tid = threadIdx.x;
    e[tid]       = e1ws[b * SKIPC + tid];
    e[tid + 256] = e1ws[b * SKIPC + tid + 256];
    __syncthreads();
    const int o_l = tid >> 3, kp = tid & 7;
    const int cls = og * 32 + o_l;
    const float* w = W2 + (size_t)cls * SKIPC + kp * 64;
    const float* ep = e + kp * 64;
    float a = 0.f;
    #pragma unroll 8
    for (int j = 0; j < 64; ++j) a = fmaf(w[j], ep[j], a);
    part[tid] = a;
    __syncthreads();
    if (tid < 32) {
        float r = b2[og * 32 + tid];
        #pragma unroll
        for (int k = 0; k < 8; ++k) r += part[tid * 8 + k];
        out[b * NCLSC + og * 32 + tid] = r;
    }
}

extern "C" void kernel_launch(void* const* d_in, const int* in_sizes, int n_in,
                              void* d_out, int out_size, void* d_ws, size_t ws_size,
                              hipStream_t stream)
{
    const float* x   = (const float*)d_in[0];
    const float* Wst = (const float*)d_in[1];
    const float* bst = (const float*)d_in[2];
    const float* Wd  = (const float*)d_in[3];
    const float* bd  = (const float*)d_in[4];
    const float* Wr  = (const float*)d_in[5];
    const float* br  = (const float*)d_in[6];
    const float* Ws  = (const float*)d_in[7];
    const float* bs  = (const float*)d_in[8];
    const float* W1  = (const float*)d_in[9];
    const float* b1  = (const float*)d_in[10];
    const float* W2  = (const float*)d_in[11];
    const float* b2  = (const float*)d_in[12];
    float* out = (float*)d_out;

    // hbC size: per layer, BATCH * ntiles * Ci cols of 256 bf16 (Ci = min(dil_next,64))
    size_t hbC_shorts = 0;
    {
        int rem = 3069;
        for (int i = 0; i < NLAYERS; ++i) {
            int d = 1 << (i % 10);
            rem -= d;
            int ntl = (1 + rem + 63) >> 6;
            int dn = (i < NLAYERS - 1) ? (1 << ((i + 1) % 10)) : 0;
            int Ci = (dn < NT) ? dn : NT;
            hbC_shorts += (size_t)BATCH * ntl * Ci * RES;
        }
    }

    char* w = (char*)d_ws;
    float* hf     = (float*)w;     w += (size_t)BATCH * TBUF * RES * 4;
    ushort_t* hb0 = (ushort_t*)w;  w += (size_t)BATCH * TBUF * RES * 2;
    ushort_t* Asw = (ushort_t*)w;  w += (size_t)NLAYERS * RES * 512 * 2;
    ushort_t* Rsw = (ushort_t*)w;  w += (size_t)NLAYERS * RES * RES * 2;
    ushort_t* WsT = (ushort_t*)w;  w += (size_t)NLAYERS * RES * SKIPC * 2;
    float* gstore = (float*)w;     w += (size_t)NLAYERS * BATCH * RES * 4;
    float* skip   = (float*)w;     w += (size_t)BATCH * SKIPC * 4;
    float* e1ws   = (float*)w;     w += (size_t)BATCH * SKIPC * 4;
    ushort_t* hbC = (ushort_t*)w;  w += hbC_shorts * 2;
    int* flg      = (int*)w;       w += (size_t)NLAYERS * BATCH * MAXTILES * 4;

    prep_kernel<<<38400, 256, 0, stream>>>(Wd, Wr, Ws, Asw, Rsw, WsT);
    start_kernel<<<(BATCH * TBUF * RES) / 256, 256, 0, stream>>>(x, Wst, bst, hf, hb0);
    hipMemsetAsync(skip, 0, BATCH * SKIPC * 4, stream);
    hipMemsetAsync(flg, 0, (size_t)NLAYERS * BATCH * MAXTILES * 4, stream);

    fused_layers_kernel<<<GRIDP, 512, 0, stream>>>(
        hf, hb0, Asw, bd, Rsw, br, gstore, hbC, flg);

    skip_kernel<<<dim3(NLAYERS, BATCH), 512, 0, stream>>>(WsT, bs, gstore, skip);
    end1_kernel<<<dim3(BATCH, 16), 256, 0, stream>>>(skip, W1, b1, e1ws);
    end2_kernel<<<dim3(BATCH, 8), 256, 0, stream>>>(e1ws, W2, b2, out);
}